// Round 1
// baseline (2157.759 us; speedup 1.0000x reference)
//
#include <hip/hip_runtime.h>

#define EPS 1e-3f

// ws float layout:
// [0,96)      W0f[k*32+c]  = w_pos[k][c] * s0[c]
// [96,128)    B0f[c]       = bn0_b[c] - bn0_m[c]*s0[c]
// [128,1152)  W1f[k*32+c]  = w1[k][c] * s1[c]
// [1152,1184) B1f[c]       = (b1[c] - bn1_m[c])*s1[c] + bn1_b[c]
// [1184, 1184 + n_ref*32)  ref2[n*32+c] = BNf(ref_feat @ w_feat)

__global__ void prep_kernel(const float* __restrict__ w_pos,
                            const float* __restrict__ g0, const float* __restrict__ b0,
                            const float* __restrict__ m0, const float* __restrict__ v0,
                            const float* __restrict__ w1, const float* __restrict__ b1lin,
                            const float* __restrict__ g1, const float* __restrict__ b1bn,
                            const float* __restrict__ m1, const float* __restrict__ v1,
                            float* __restrict__ ws) {
    int c = threadIdx.x;
    if (c >= 32) return;
    float s0 = g0[c] * rsqrtf(v0[c] + EPS);
    #pragma unroll
    for (int k = 0; k < 3; ++k) ws[k * 32 + c] = w_pos[k * 32 + c] * s0;
    ws[96 + c] = b0[c] - m0[c] * s0;
    float s1 = g1[c] * rsqrtf(v1[c] + EPS);
    #pragma unroll
    for (int k = 0; k < 32; ++k) ws[128 + k * 32 + c] = w1[k * 32 + c] * s1;
    ws[1152 + c] = (b1lin[c] - m1[c]) * s1 + b1bn[c];
}

__global__ __launch_bounds__(256)
void node_kernel(const float* __restrict__ feat, const float* __restrict__ wf,
                 const float* __restrict__ gf, const float* __restrict__ bf,
                 const float* __restrict__ mf, const float* __restrict__ vf,
                 float* __restrict__ ref2, int n_ref) {
    int idx = blockIdx.x * blockDim.x + threadIdx.x;
    if (idx >= n_ref * 32) return;
    int n = idx >> 5, c = idx & 31;
    float acc = 0.f;
    #pragma unroll
    for (int k = 0; k < 16; ++k) acc = fmaf(feat[n * 16 + k], wf[k * 32 + c], acc);
    float s = gf[c] * rsqrtf(vf[c] + EPS);
    ref2[idx] = (acc - mf[c]) * s + bf[c];
}

__global__ __launch_bounds__(256)
void edge_kernel(const float4* __restrict__ ref_bxyz, const float4* __restrict__ query_bxyz,
                 const int* __restrict__ e_ref, const int* __restrict__ e_query,
                 const float* __restrict__ ws, int* __restrict__ out, int E) {
    int e = blockIdx.x * blockDim.x + threadIdx.x;
    if (e >= E) return;
    int r = e_ref[e];
    int q = e_query[e];
    float4 rb = ref_bxyz[r];
    float4 qb = query_bxyz[q];
    float d0 = rb.y - qb.y, d1 = rb.z - qb.z, d2 = rb.w - qb.w;

    const float* __restrict__ W0 = ws;
    const float* __restrict__ B0 = ws + 96;
    const float* __restrict__ W1 = ws + 128;
    const float* __restrict__ B1 = ws + 1152;
    const float4* __restrict__ r4 = (const float4*)(ws + 1184 + (size_t)r * 32);

    // gather precomputed node features (vectorized)
    float rf[32];
    #pragma unroll
    for (int j = 0; j < 8; ++j) {
        float4 t = r4[j];
        rf[4 * j + 0] = t.x; rf[4 * j + 1] = t.y;
        rf[4 * j + 2] = t.z; rf[4 * j + 3] = t.w;
    }

    // h = relu(pos_diff @ W0f + B0f + ref2[r])
    float h[32];
    #pragma unroll
    for (int c = 0; c < 32; ++c) {
        float t = fmaf(d0, W0[c], fmaf(d1, W0[32 + c], fmaf(d2, W0[64 + c], B0[c])));
        h[c] = fmaxf(t + rf[c], 0.f);
    }

    // y = relu(h @ W1f + B1f)
    float acc[32];
    #pragma unroll
    for (int c = 0; c < 32; ++c) acc[c] = B1[c];
    #pragma unroll
    for (int k = 0; k < 32; ++k) {
        float hk = h[k];
        #pragma unroll
        for (int c = 0; c < 32; ++c) acc[c] = fmaf(hk, W1[k * 32 + c], acc[c]);
    }

    // scatter-max: values are >= 0 after relu, so int-compare == float-compare
    int base = q * 32;
    #pragma unroll
    for (int c = 0; c < 32; ++c) {
        float y = fmaxf(acc[c], 0.f);
        atomicMax(&out[base + c], __float_as_int(y));
    }
}

extern "C" void kernel_launch(void* const* d_in, const int* in_sizes, int n_in,
                              void* d_out, int out_size, void* d_ws, size_t ws_size,
                              hipStream_t stream) {
    const float* ref_bxyz   = (const float*)d_in[0];
    const float* ref_feat   = (const float*)d_in[1];
    const float* query_bxyz = (const float*)d_in[2];
    const int*   e_ref      = (const int*)d_in[3];
    const int*   e_query    = (const int*)d_in[4];
    const float* w_pos      = (const float*)d_in[5];
    const float* bn0_g = (const float*)d_in[6];
    const float* bn0_b = (const float*)d_in[7];
    const float* bn0_m = (const float*)d_in[8];
    const float* bn0_v = (const float*)d_in[9];
    const float* w_feat = (const float*)d_in[10];
    const float* bnf_g = (const float*)d_in[11];
    const float* bnf_b = (const float*)d_in[12];
    const float* bnf_m = (const float*)d_in[13];
    const float* bnf_v = (const float*)d_in[14];
    const float* w1    = (const float*)d_in[15];
    const float* b1    = (const float*)d_in[16];
    const float* bn1_g = (const float*)d_in[17];
    const float* bn1_b = (const float*)d_in[18];
    const float* bn1_m = (const float*)d_in[19];
    const float* bn1_v = (const float*)d_in[20];

    int n_ref = in_sizes[0] / 4;
    int E     = in_sizes[3];

    float* ws = (float*)d_ws;
    float* ref2 = ws + 1184;

    // output init to 0 (matches empty-segment->0 and relu>=0 semantics)
    hipMemsetAsync(d_out, 0, (size_t)out_size * sizeof(float), stream);

    prep_kernel<<<1, 32, 0, stream>>>(w_pos, bn0_g, bn0_b, bn0_m, bn0_v,
                                      w1, b1, bn1_g, bn1_b, bn1_m, bn1_v, ws);

    int node_threads = n_ref * 32;
    node_kernel<<<(node_threads + 255) / 256, 256, 0, stream>>>(
        ref_feat, w_feat, bnf_g, bnf_b, bnf_m, bnf_v, ref2, n_ref);

    edge_kernel<<<(E + 255) / 256, 256, 0, stream>>>(
        (const float4*)ref_bxyz, (const float4*)query_bxyz,
        e_ref, e_query, ws, (int*)d_out, E);
}

// Round 2
// 526.788 us; speedup vs baseline: 4.0961x; 4.0961x over previous
//
#include <hip/hip_runtime.h>

#define EPS 1e-3f
#define QPB 8
#define SLOTS 384
#define LDS_STRIDE 33

// ws float layout:
// [0,96)      W0f[k*32+c]; [96,128) B0f; [128,1152) W1f; [1152,1184) B1f
// [1184, +n_ref*32)  ref2
// then int arrays: count[n_q], cursor[n_q], psum[256], boff[256], offs[n_q+4], sorted[E]

__global__ void prep_kernel(const float* __restrict__ w_pos,
                            const float* __restrict__ g0, const float* __restrict__ b0,
                            const float* __restrict__ m0, const float* __restrict__ v0,
                            const float* __restrict__ w1, const float* __restrict__ b1lin,
                            const float* __restrict__ g1, const float* __restrict__ b1bn,
                            const float* __restrict__ m1, const float* __restrict__ v1,
                            float* __restrict__ ws) {
    int c = threadIdx.x;
    if (c >= 32) return;
    float s0 = g0[c] * rsqrtf(v0[c] + EPS);
    #pragma unroll
    for (int k = 0; k < 3; ++k) ws[k * 32 + c] = w_pos[k * 32 + c] * s0;
    ws[96 + c] = b0[c] - m0[c] * s0;
    float s1 = g1[c] * rsqrtf(v1[c] + EPS);
    #pragma unroll
    for (int k = 0; k < 32; ++k) ws[128 + k * 32 + c] = w1[k * 32 + c] * s1;
    ws[1152 + c] = (b1lin[c] - m1[c]) * s1 + b1bn[c];
}

__global__ __launch_bounds__(256)
void node_kernel(const float* __restrict__ feat, const float* __restrict__ wf,
                 const float* __restrict__ gf, const float* __restrict__ bf,
                 const float* __restrict__ mf, const float* __restrict__ vf,
                 float* __restrict__ ref2, int n_ref) {
    int idx = blockIdx.x * blockDim.x + threadIdx.x;
    if (idx >= n_ref * 32) return;
    int n = idx >> 5, c = idx & 31;
    float acc = 0.f;
    #pragma unroll
    for (int k = 0; k < 16; ++k) acc = fmaf(feat[n * 16 + k], wf[k * 32 + c], acc);
    float s = gf[c] * rsqrtf(vf[c] + EPS);
    ref2[idx] = (acc - mf[c]) * s + bf[c];
}

__global__ __launch_bounds__(256)
void hist_kernel(const int* __restrict__ e_query, int* __restrict__ count, int E) {
    int e = blockIdx.x * blockDim.x + threadIdx.x;
    if (e < E) atomicAdd(&count[e_query[e]], 1);
}

// ---- 3-kernel hierarchical exclusive scan over count[n_q] -> offs[n_q+1] ----
__global__ __launch_bounds__(256)
void scan_part(const int* __restrict__ count, int* __restrict__ psum, int n_q) {
    __shared__ int s[256];
    int i = blockIdx.x * 256 + threadIdx.x;
    int v = (i < n_q) ? count[i] : 0;
    s[threadIdx.x] = v;
    __syncthreads();
    for (int d = 128; d > 0; d >>= 1) {
        if (threadIdx.x < d) s[threadIdx.x] += s[threadIdx.x + d];
        __syncthreads();
    }
    if (threadIdx.x == 0) psum[blockIdx.x] = s[0];
}

__global__ __launch_bounds__(256)
void scan_top(const int* __restrict__ psum, int* __restrict__ boff, int nb) {
    __shared__ int s[256];
    int t = threadIdx.x;
    int v = (t < nb) ? psum[t] : 0;
    s[t] = v;
    __syncthreads();
    for (int d = 1; d < 256; d <<= 1) {
        int x = (t >= d) ? s[t - d] : 0;
        __syncthreads();
        s[t] += x;
        __syncthreads();
    }
    boff[t] = s[t] - v;  // exclusive
}

__global__ __launch_bounds__(256)
void scan_final(const int* __restrict__ count, const int* __restrict__ boff,
                int* __restrict__ offs, int n_q) {
    __shared__ int s[256];
    int t = threadIdx.x;
    int i = blockIdx.x * 256 + t;
    int v = (i < n_q) ? count[i] : 0;
    s[t] = v;
    __syncthreads();
    for (int d = 1; d < 256; d <<= 1) {
        int x = (t >= d) ? s[t - d] : 0;
        __syncthreads();
        s[t] += x;
        __syncthreads();
    }
    int excl = boff[blockIdx.x] + s[t] - v;
    if (i < n_q) {
        offs[i] = excl;
        if (i == n_q - 1) offs[n_q] = excl + v;
    }
}

__global__ __launch_bounds__(256)
void scatter_kernel(const int* __restrict__ e_query, const int* __restrict__ offs,
                    int* __restrict__ cursor, int* __restrict__ sorted, int E) {
    int e = blockIdx.x * blockDim.x + threadIdx.x;
    if (e >= E) return;
    int q = e_query[e];
    int pos = offs[q] + atomicAdd(&cursor[q], 1);
    sorted[pos] = e;
}

__global__ __launch_bounds__(256)
void fused_kernel(const float4* __restrict__ ref_bxyz, const float4* __restrict__ query_bxyz,
                  const int* __restrict__ e_ref, const int* __restrict__ sorted,
                  const int* __restrict__ offs, const float* __restrict__ ws,
                  float* __restrict__ out, int n_q) {
    __shared__ float sy[SLOTS * LDS_STRIDE];
    __shared__ int soff[QPB + 1];
    int t = threadIdx.x;
    int q0 = blockIdx.x * QPB;
    if (t <= QPB) soff[t] = offs[min(q0 + t, n_q)];
    __syncthreads();
    int base = soff[0], end = soff[QPB];

    const float* __restrict__ W0 = ws;
    const float* __restrict__ B0 = ws + 96;
    const float* __restrict__ W1 = ws + 128;
    const float* __restrict__ B1 = ws + 1152;
    const float* __restrict__ ref2 = ws + 1184;

    int qi = t >> 5, c = t & 31;
    float m = 0.f;

    for (int slab = base; slab < end; slab += SLOTS) {
        int nslab = min(end - slab, SLOTS);
        // ---- compute phase: per-slot edge MLP into LDS ----
        for (int s = t; s < nslab; s += 256) {
            int slot = slab + s;
            int e = sorted[slot];
            int r = e_ref[e];
            // which of the 8 queries does this slot belong to?
            int ql = 0;
            #pragma unroll
            for (int j = 1; j < QPB; ++j) ql += (slot >= soff[j]) ? 1 : 0;
            int q = q0 + ql;

            float4 rb = ref_bxyz[r];
            float4 qb = query_bxyz[q];
            float d0 = rb.y - qb.y, d1 = rb.z - qb.z, d2 = rb.w - qb.w;

            const float4* __restrict__ r4 = (const float4*)(ref2 + (size_t)r * 32);
            float rf[32];
            #pragma unroll
            for (int j = 0; j < 8; ++j) {
                float4 tv = r4[j];
                rf[4 * j + 0] = tv.x; rf[4 * j + 1] = tv.y;
                rf[4 * j + 2] = tv.z; rf[4 * j + 3] = tv.w;
            }
            float h[32];
            #pragma unroll
            for (int cc = 0; cc < 32; ++cc) {
                float tv = fmaf(d0, W0[cc], fmaf(d1, W0[32 + cc], fmaf(d2, W0[64 + cc], B0[cc])));
                h[cc] = fmaxf(tv + rf[cc], 0.f);
            }
            float acc[32];
            #pragma unroll
            for (int cc = 0; cc < 32; ++cc) acc[cc] = B1[cc];
            #pragma unroll
            for (int k = 0; k < 32; ++k) {
                float hk = h[k];
                #pragma unroll
                for (int cc = 0; cc < 32; ++cc) acc[cc] = fmaf(hk, W1[k * 32 + cc], acc[cc]);
            }
            #pragma unroll
            for (int cc = 0; cc < 32; ++cc)
                sy[s * LDS_STRIDE + cc] = fmaxf(acc[cc], 0.f);
        }
        __syncthreads();
        // ---- reduce phase: thread (qi,c) maxes its query's rows in this slab ----
        int lo = max(soff[qi] - slab, 0);
        int hi = min(soff[qi + 1] - slab, nslab);
        for (int s = lo; s < hi; ++s) m = fmaxf(m, sy[s * LDS_STRIDE + c]);
        __syncthreads();
    }
    if (q0 + qi < n_q) out[(size_t)(q0 + qi) * 32 + c] = m;
}

extern "C" void kernel_launch(void* const* d_in, const int* in_sizes, int n_in,
                              void* d_out, int out_size, void* d_ws, size_t ws_size,
                              hipStream_t stream) {
    const float* ref_bxyz   = (const float*)d_in[0];
    const float* ref_feat   = (const float*)d_in[1];
    const float* query_bxyz = (const float*)d_in[2];
    const int*   e_ref      = (const int*)d_in[3];
    const int*   e_query    = (const int*)d_in[4];
    const float* w_pos      = (const float*)d_in[5];
    const float* bn0_g = (const float*)d_in[6];
    const float* bn0_b = (const float*)d_in[7];
    const float* bn0_m = (const float*)d_in[8];
    const float* bn0_v = (const float*)d_in[9];
    const float* w_feat = (const float*)d_in[10];
    const float* bnf_g = (const float*)d_in[11];
    const float* bnf_b = (const float*)d_in[12];
    const float* bnf_m = (const float*)d_in[13];
    const float* bnf_v = (const float*)d_in[14];
    const float* w1    = (const float*)d_in[15];
    const float* b1    = (const float*)d_in[16];
    const float* bn1_g = (const float*)d_in[17];
    const float* bn1_b = (const float*)d_in[18];
    const float* bn1_m = (const float*)d_in[19];
    const float* bn1_v = (const float*)d_in[20];

    int n_ref = in_sizes[0] / 4;
    int n_q   = in_sizes[2] / 4;
    int E     = in_sizes[3];

    float* ws = (float*)d_ws;
    float* ref2 = ws + 1184;

    // int-array layout after ref2
    size_t fi = 1184 + (size_t)n_ref * 32;
    int* count  = (int*)(ws + fi);
    int* cursor = count + n_q;
    int* psum   = cursor + n_q;
    int* boff   = psum + 256;
    int* offs   = boff + 256;
    int* sorted = offs + ((n_q + 4) & ~3);

    int nb = (n_q + 255) / 256;

    prep_kernel<<<1, 32, 0, stream>>>(w_pos, bn0_g, bn0_b, bn0_m, bn0_v,
                                      w1, b1, bn1_g, bn1_b, bn1_m, bn1_v, ws);

    int node_threads = n_ref * 32;
    node_kernel<<<(node_threads + 255) / 256, 256, 0, stream>>>(
        ref_feat, w_feat, bnf_g, bnf_b, bnf_m, bnf_v, ref2, n_ref);

    hipMemsetAsync(count, 0, (size_t)2 * n_q * sizeof(int), stream);  // count + cursor

    hist_kernel<<<(E + 255) / 256, 256, 0, stream>>>(e_query, count, E);

    scan_part<<<nb, 256, 0, stream>>>(count, psum, n_q);
    scan_top<<<1, 256, 0, stream>>>(psum, boff, nb);
    scan_final<<<nb, 256, 0, stream>>>(count, boff, offs, n_q);

    scatter_kernel<<<(E + 255) / 256, 256, 0, stream>>>(e_query, offs, cursor, sorted, E);

    int fblocks = (n_q + QPB - 1) / QPB;
    fused_kernel<<<fblocks, 256, 0, stream>>>(
        (const float4*)ref_bxyz, (const float4*)query_bxyz,
        e_ref, sorted, offs, ws, (float*)d_out, n_q);
}